// Round 2
// baseline (129.142 us; speedup 1.0000x reference)
//
#include <hip/hip_runtime.h>
#include <hip/hip_bf16.h>
#include <math.h>

typedef __bf16 bf16x8 __attribute__((ext_vector_type(8)));
typedef float  f32x4  __attribute__((ext_vector_type(4)));

#define NND 8192
#define DIM 64

__device__ __forceinline__ float wsum(float v) {
#pragma unroll
    for (int m = 1; m < 64; m <<= 1) v += __shfl_xor(v, m, 64);
    return v;
}

struct SC { float sh, ch; };
__device__ __forceinline__ SC sinhcosh(float c) {
    float e  = expf(c);
    float ei = 1.0f / e;
    SC r; r.sh = 0.5f * (e - ei); r.ch = 0.5f * (e + ei);
    return r;
}

// arcosh(max(sqrt(1+n2), 1+1e-7)) computed WITHOUT th*th-1 cancellation.
// Matches ref: proj gives x0=sqrt(1+n2); logmap0 clips at 1+1e-7 (i.e. n2 at ~2e-7).
__device__ __forceinline__ float arcosh_from_n2(float n2) {
    float t = fmaxf(n2, 2.0000001e-7f);
    return logf(sqrtf(1.0f + t) + sqrtf(t));
}

// L = logmap0(proj(expmap0(proj_tan0(x)))) for one row; lane holds dim `lane`.
__device__ __forceinline__ float tangent_chain(float xv, int lane) {
    float y   = (lane == 0) ? 0.0f : xv;
    float yn2 = wsum(y * y);
    float yn  = fmaxf(sqrtf(fmaxf(yn2, 1e-30f)), 1e-15f);
    SC s1 = sinhcosh(fminf(yn, 15.0f));
    float r   = (lane == 0) ? 0.0f : s1.sh * y / yn;
    float rn2 = wsum(r * r);
    float ynb = fmaxf(sqrtf(fmaxf(rn2, 1e-30f)), 1e-15f);
    float ac  = arcosh_from_n2(rn2);
    return (lane == 0) ? 0.0f : ac * r / ynb;
}

// From m = logmap0(xh) @ W^T through expmap0 -> mobius_add(., hyp_bias) -> logmap0.
// ubv = logmap0(hyp_bias)[lane]; theta_b = |ub| (Minkowski norm of the transported
// tangent — EXACT by transport isometry; avoids the fp32 catastrophic cancellation
// in mdot(v,v) = |w|^2 - v0^2 where both terms are ~(alpha*res0)^2 ~ 1e8).
__device__ __forceinline__ float second_chain(float m, float ubv, float theta_b, int lane) {
    float my  = (lane == 0) ? 0.0f : m;
    float mn2 = wsum(my * my);
    float mn  = fmaxf(sqrtf(fmaxf(mn2, 1e-30f)), 1e-15f);
    SC s2 = sinhcosh(fminf(mn, 15.0f));
    float rr   = (lane == 0) ? 0.0f : s2.sh * my / mn;
    float rrn2 = wsum(rr * rr);
    float res0 = sqrtf(fmaxf(1.0f + rrn2, 1e-7f));
    // ptransp0(res, ub)
    float yn3   = fmaxf(sqrtf(fmaxf(rrn2, 1e-30f)), 1e-15f);
    float yhat  = (lane == 0) ? 0.0f : rr / yn3;
    float alpha = wsum(yhat * ubv);
    float w_    = ubv - alpha * (1.0f - res0) * yhat;  // spatial part (lane0 -> 0)
    float ux    = wsum(rr * w_);                       // lane0: rr = 0
    float v0    = ux / fmaxf(res0, 1e-7f);
    float vv    = (lane == 0) ? v0 : w_;
    float resv  = (lane == 0) ? res0 : rr;
    // expmap(v, res) with theta = |ub| (stable, constant across rows)
    float theta = theta_b;
    SC s3 = sinhcosh(fminf(theta, 15.0f));
    float pv  = s3.ch * resv + s3.sh * vv / theta;
    float pn2 = wsum((lane == 0) ? 0.0f : pv * pv);
    float yn4 = fmaxf(sqrtf(fmaxf(pn2, 1e-30f)), 1e-15f);
    float ac4 = arcosh_from_n2(pn2);
    return (lane == 0) ? 0.0f : ac4 * pv / yn4;
}

// h_tan -> out = proj(expmap0(proj_tan0(leaky_relu(logmap0(proj(expmap0(h_tan)))))))
__device__ __forceinline__ float epilogue_chain(float hv, int lane) {
    float y   = (lane == 0) ? 0.0f : hv;
    float yn2 = wsum(y * y);
    float yn  = fmaxf(sqrtf(fmaxf(yn2, 1e-30f)), 1e-15f);
    SC s1 = sinhcosh(fminf(yn, 15.0f));
    float r   = (lane == 0) ? 0.0f : s1.sh * y / yn;
    float rn2 = wsum(r * r);
    float ynb = fmaxf(sqrtf(fmaxf(rn2, 1e-30f)), 1e-15f);
    float ac  = arcosh_from_n2(rn2);
    float lgv = (lane == 0) ? 0.0f : ac * r / ynb;
    float t   = (lgv > 0.0f) ? lgv : 0.01f * lgv;      // leaky_relu
    float tn2 = wsum(t * t);
    float tn  = fmaxf(sqrtf(fmaxf(tn2, 1e-30f)), 1e-15f);
    SC s3 = sinhcosh(fminf(tn, 15.0f));
    float ov  = (lane == 0) ? 0.0f : s3.sh * t / tn;
    float on2 = wsum(ov * ov);
    float o0  = sqrtf(fmaxf(1.0f + on2, 1e-7f));
    return (lane == 0) ? o0 : ov;
}

// Kernel 1: per-row chain + 64x64 matvec; writes B operand transposed in bf16.
__global__ __launch_bounds__(256) void k_prep(
    const float* __restrict__ x, const float* __restrict__ weight,
    const float* __restrict__ bias, __bf16* __restrict__ l2bfT)
{
    __shared__ float WL[64][65];
    __shared__ float ubuf[64];
    const int tid  = threadIdx.x;
    const int lane = tid & 63;
    const int wave = tid >> 6;
#pragma unroll
    for (int i = 0; i < 16; ++i) {
        int idx = i * 256 + tid;
        WL[idx >> 6][idx & 63] = weight[idx];
    }
    if (wave == 0) {
        float bv = bias[lane];
        ubuf[lane] = tangent_chain(bv, lane);
    }
    __syncthreads();
    const float ubv = ubuf[lane];
    // theta_b = clip chain on |ub| (mnorm + expmap clips, all inactive here but kept)
    float nub2 = wsum(ubv * ubv);
    float thb  = fmaxf(fminf(sqrtf(fmaxf(nub2, 1e-7f)), 1e6f), 1e-15f);
    const int rowbase = blockIdx.x * 32 + wave * 8;
    for (int i = 0; i < 8; ++i) {
        int row = rowbase + i;
        float xv  = x[row * 64 + lane];
        float L1v = tangent_chain(xv, lane);
        float mj = 0.0f;
#pragma unroll
        for (int d = 0; d < 64; ++d)
            mj = fmaf(__shfl(L1v, d, 64), WL[lane][d], mj);
        float L2v = second_chain(mj, ubv, thb, lane);
        l2bfT[(size_t)lane * NND + row] = (__bf16)L2v;
    }
}

// Kernel 2: h_tan = adj @ L2 via bf16 MFMA (on-the-fly fp32->bf16 of adj), fused epilogue.
// BM=16 rows/block, waves K-split (2048 each), no barriers in K loop.
__global__ __launch_bounds__(256) void k_mm(
    const float* __restrict__ adj, const __bf16* __restrict__ l2bfT,
    float* __restrict__ out)
{
    __shared__ float Ct[4][16][65];
    const int tid  = threadIdx.x;
    const int lane = tid & 63;
    const int wave = tid >> 6;     // K-split quarter
    const int l15  = lane & 15;
    const int lg   = lane >> 4;    // 0..3
    const int rowbase = blockIdx.x * 16;

    const float*  aptr = adj + (size_t)(rowbase + l15) * NND + wave * 2048 + 8 * lg;
    const __bf16* bp0  = l2bfT + (size_t)l15 * NND + wave * 2048 + 8 * lg;
    const __bf16* bp1  = bp0 + (size_t)16 * NND;
    const __bf16* bp2  = bp0 + (size_t)32 * NND;
    const __bf16* bp3  = bp0 + (size_t)48 * NND;

    f32x4 acc0 = {0.f, 0.f, 0.f, 0.f};
    f32x4 acc1 = acc0, acc2 = acc0, acc3 = acc0;

#pragma unroll 2
    for (int k0 = 0; k0 < 2048; k0 += 64) {
#pragma unroll
        for (int ks = 0; ks < 2; ++ks) {
            const int k = k0 + 32 * ks;
            f32x4 a0 = *reinterpret_cast<const f32x4*>(aptr + k);
            f32x4 a1 = *reinterpret_cast<const f32x4*>(aptr + k + 4);
            bf16x8 av;
            av[0] = (__bf16)a0[0]; av[1] = (__bf16)a0[1];
            av[2] = (__bf16)a0[2]; av[3] = (__bf16)a0[3];
            av[4] = (__bf16)a1[0]; av[5] = (__bf16)a1[1];
            av[6] = (__bf16)a1[2]; av[7] = (__bf16)a1[3];
            bf16x8 b0 = *reinterpret_cast<const bf16x8*>(bp0 + k);
            bf16x8 b1 = *reinterpret_cast<const bf16x8*>(bp1 + k);
            bf16x8 b2 = *reinterpret_cast<const bf16x8*>(bp2 + k);
            bf16x8 b3 = *reinterpret_cast<const bf16x8*>(bp3 + k);
            acc0 = __builtin_amdgcn_mfma_f32_16x16x32_bf16(av, b0, acc0, 0, 0, 0);
            acc1 = __builtin_amdgcn_mfma_f32_16x16x32_bf16(av, b1, acc1, 0, 0, 0);
            acc2 = __builtin_amdgcn_mfma_f32_16x16x32_bf16(av, b2, acc2, 0, 0, 0);
            acc3 = __builtin_amdgcn_mfma_f32_16x16x32_bf16(av, b3, acc3, 0, 0, 0);
        }
    }

    // C/D layout (verified): col = lane&15, row = (lane>>4)*4 + reg
#pragma unroll
    for (int i = 0; i < 4; ++i) {
        Ct[wave][lg * 4 + i][ 0 + l15] = acc0[i];
        Ct[wave][lg * 4 + i][16 + l15] = acc1[i];
        Ct[wave][lg * 4 + i][32 + l15] = acc2[i];
        Ct[wave][lg * 4 + i][48 + l15] = acc3[i];
    }
    __syncthreads();

    for (int i = 0; i < 4; ++i) {
        int r = wave * 4 + i;
        float hv = Ct[0][r][lane] + Ct[1][r][lane] + Ct[2][r][lane] + Ct[3][r][lane];
        float o  = epilogue_chain(hv, lane);
        out[(size_t)(rowbase + r) * 64 + lane] = o;
    }
}

extern "C" void kernel_launch(void* const* d_in, const int* in_sizes, int n_in,
                              void* d_out, int out_size, void* d_ws, size_t ws_size,
                              hipStream_t stream)
{
    const float* x      = (const float*)d_in[0];
    const float* adj    = (const float*)d_in[1];
    const float* weight = (const float*)d_in[2];
    const float* bias   = (const float*)d_in[3];
    float* out = (float*)d_out;
    __bf16* l2bfT = (__bf16*)d_ws;   // 64 x 8192 bf16 = 1 MB

    k_prep<<<256, 256, 0, stream>>>(x, weight, bias, l2bfT);
    k_mm<<<512, 256, 0, stream>>>(adj, l2bfT, out);
}

// Round 3
// 114.494 us; speedup vs baseline: 1.1279x; 1.1279x over previous
//
#include <hip/hip_runtime.h>
#include <hip/hip_bf16.h>
#include <math.h>

typedef __bf16 bf16x8 __attribute__((ext_vector_type(8)));
typedef float  f32x4  __attribute__((ext_vector_type(4)));

#define NND 8192
#define DIM 64

__device__ __forceinline__ float wsum(float v) {
#pragma unroll
    for (int m = 1; m < 64; m <<= 1) v += __shfl_xor(v, m, 64);
    return v;
}

struct SC { float sh, ch; };
__device__ __forceinline__ SC sinhcosh(float c) {
    float e  = expf(c);
    float ei = 1.0f / e;
    SC r; r.sh = 0.5f * (e - ei); r.ch = 0.5f * (e + ei);
    return r;
}

// arcosh(max(sqrt(1+n2), 1+1e-7)) WITHOUT th*th-1 cancellation.
__device__ __forceinline__ float arcosh_from_n2(float n2) {
    float t = fmaxf(n2, 2.0000001e-7f);
    return logf(sqrtf(1.0f + t) + sqrtf(t));
}

// L = logmap0(proj(expmap0(proj_tan0(x)))) for one row; lane holds dim `lane`.
__device__ __forceinline__ float tangent_chain(float xv, int lane) {
    float y   = (lane == 0) ? 0.0f : xv;
    float yn2 = wsum(y * y);
    float yn  = fmaxf(sqrtf(fmaxf(yn2, 1e-30f)), 1e-15f);
    SC s1 = sinhcosh(fminf(yn, 15.0f));
    float r   = (lane == 0) ? 0.0f : s1.sh * y / yn;
    float rn2 = wsum(r * r);
    float ynb = fmaxf(sqrtf(fmaxf(rn2, 1e-30f)), 1e-15f);
    float ac  = arcosh_from_n2(rn2);
    return (lane == 0) ? 0.0f : ac * r / ynb;
}

// expmap0 -> mobius_add(., hyp_bias) -> logmap0, theta = |ub| (transport isometry,
// avoids fp32 catastrophic cancellation in mdot(v,v)).
__device__ __forceinline__ float second_chain(float m, float ubv, float theta_b, int lane) {
    float my  = (lane == 0) ? 0.0f : m;
    float mn2 = wsum(my * my);
    float mn  = fmaxf(sqrtf(fmaxf(mn2, 1e-30f)), 1e-15f);
    SC s2 = sinhcosh(fminf(mn, 15.0f));
    float rr   = (lane == 0) ? 0.0f : s2.sh * my / mn;
    float rrn2 = wsum(rr * rr);
    float res0 = sqrtf(fmaxf(1.0f + rrn2, 1e-7f));
    float yn3   = fmaxf(sqrtf(fmaxf(rrn2, 1e-30f)), 1e-15f);
    float yhat  = (lane == 0) ? 0.0f : rr / yn3;
    float alpha = wsum(yhat * ubv);
    float w_    = ubv - alpha * (1.0f - res0) * yhat;
    float ux    = wsum(rr * w_);
    float v0    = ux / fmaxf(res0, 1e-7f);
    float vv    = (lane == 0) ? v0 : w_;
    float resv  = (lane == 0) ? res0 : rr;
    float theta = theta_b;
    SC s3 = sinhcosh(fminf(theta, 15.0f));
    float pv  = s3.ch * resv + s3.sh * vv / theta;
    float pn2 = wsum((lane == 0) ? 0.0f : pv * pv);
    float yn4 = fmaxf(sqrtf(fmaxf(pn2, 1e-30f)), 1e-15f);
    float ac4 = arcosh_from_n2(pn2);
    return (lane == 0) ? 0.0f : ac4 * pv / yn4;
}

// h_tan -> final output chain.
__device__ __forceinline__ float epilogue_chain(float hv, int lane) {
    float y   = (lane == 0) ? 0.0f : hv;
    float yn2 = wsum(y * y);
    float yn  = fmaxf(sqrtf(fmaxf(yn2, 1e-30f)), 1e-15f);
    SC s1 = sinhcosh(fminf(yn, 15.0f));
    float r   = (lane == 0) ? 0.0f : s1.sh * y / yn;
    float rn2 = wsum(r * r);
    float ynb = fmaxf(sqrtf(fmaxf(rn2, 1e-30f)), 1e-15f);
    float ac  = arcosh_from_n2(rn2);
    float lgv = (lane == 0) ? 0.0f : ac * r / ynb;
    float t   = (lgv > 0.0f) ? lgv : 0.01f * lgv;
    float tn2 = wsum(t * t);
    float tn  = fmaxf(sqrtf(fmaxf(tn2, 1e-30f)), 1e-15f);
    SC s3 = sinhcosh(fminf(tn, 15.0f));
    float ov  = (lane == 0) ? 0.0f : s3.sh * t / tn;
    float on2 = wsum(ov * ov);
    float o0  = sqrtf(fmaxf(1.0f + on2, 1e-7f));
    return (lane == 0) ? o0 : ov;
}

// Kernel 1: per-row chain + 64x64 matvec; 1 row per wave, 2048 blocks (full occupancy).
__global__ __launch_bounds__(256) void k_prep(
    const float* __restrict__ x, const float* __restrict__ weight,
    const float* __restrict__ bias, __bf16* __restrict__ l2bfT)
{
    __shared__ float WL[64][65];
    const int tid  = threadIdx.x;
    const int lane = tid & 63;
    const int wave = tid >> 6;
#pragma unroll
    for (int i = 0; i < 16; ++i) {
        int idx = i * 256 + tid;
        WL[idx >> 6][idx & 63] = weight[idx];
    }
    __syncthreads();
    // every wave computes the bias tangent itself (no cross-wave sync)
    float ubv  = tangent_chain(bias[lane], lane);
    float nub2 = wsum(ubv * ubv);
    float thb  = fmaxf(fminf(sqrtf(fmaxf(nub2, 1e-7f)), 1e6f), 1e-15f);

    const int row = blockIdx.x * 4 + wave;
    float xv  = x[row * 64 + lane];
    float L1v = tangent_chain(xv, lane);
    float mj0 = 0.f, mj1 = 0.f, mj2 = 0.f, mj3 = 0.f;
#pragma unroll
    for (int d = 0; d < 64; d += 4) {
        mj0 = fmaf(__shfl(L1v, d,     64), WL[lane][d],     mj0);
        mj1 = fmaf(__shfl(L1v, d + 1, 64), WL[lane][d + 1], mj1);
        mj2 = fmaf(__shfl(L1v, d + 2, 64), WL[lane][d + 2], mj2);
        mj3 = fmaf(__shfl(L1v, d + 3, 64), WL[lane][d + 3], mj3);
    }
    float mj  = (mj0 + mj1) + (mj2 + mj3);
    float L2v = second_chain(mj, ubv, thb, lane);
    l2bfT[(size_t)lane * NND + row] = (__bf16)L2v;
}

// Kernel 2: h_tan = adj @ L2 via bf16 MFMA, 8-way K-split, 2-deep SW pipeline.
struct Tile { f32x4 a0, a1; bf16x8 b0, b1, b2, b3; };

__global__ __launch_bounds__(512, 4) void k_mm(
    const float* __restrict__ adj, const __bf16* __restrict__ l2bfT,
    float* __restrict__ out)
{
    __shared__ float Ct[8][16][65];
    const int tid  = threadIdx.x;
    const int lane = tid & 63;
    const int wave = tid >> 6;     // 0..7 K-split (1024 each)
    const int l15  = lane & 15;
    const int lg   = lane >> 4;    // 0..3
    const int rowbase = blockIdx.x * 16;

    const float*  aptr = adj + (size_t)(rowbase + l15) * NND + wave * 1024 + 8 * lg;
    const __bf16* bp0  = l2bfT + (size_t)l15 * NND + wave * 1024 + 8 * lg;
    const __bf16* bp1  = bp0 + (size_t)16 * NND;
    const __bf16* bp2  = bp0 + (size_t)32 * NND;
    const __bf16* bp3  = bp0 + (size_t)48 * NND;

    f32x4 acc0 = {0.f, 0.f, 0.f, 0.f};
    f32x4 acc1 = acc0, acc2 = acc0, acc3 = acc0;

    Tile T[3];
    // prologue: tiles 0,1 in flight
#pragma unroll
    for (int t = 0; t < 2; ++t) {
        const int k = t * 32;
        T[t].a0 = *reinterpret_cast<const f32x4*>(aptr + k);
        T[t].a1 = *reinterpret_cast<const f32x4*>(aptr + k + 4);
        T[t].b0 = *reinterpret_cast<const bf16x8*>(bp0 + k);
        T[t].b1 = *reinterpret_cast<const bf16x8*>(bp1 + k);
        T[t].b2 = *reinterpret_cast<const bf16x8*>(bp2 + k);
        T[t].b3 = *reinterpret_cast<const bf16x8*>(bp3 + k);
    }
#pragma unroll
    for (int t = 0; t < 32; ++t) {
        if (t + 2 < 32) {               // issue tile t+2 before computing tile t
            const int k = (t + 2) * 32;
            Tile& N = T[(t + 2) % 3];
            N.a0 = *reinterpret_cast<const f32x4*>(aptr + k);
            N.a1 = *reinterpret_cast<const f32x4*>(aptr + k + 4);
            N.b0 = *reinterpret_cast<const bf16x8*>(bp0 + k);
            N.b1 = *reinterpret_cast<const bf16x8*>(bp1 + k);
            N.b2 = *reinterpret_cast<const bf16x8*>(bp2 + k);
            N.b3 = *reinterpret_cast<const bf16x8*>(bp3 + k);
        }
        Tile& C = T[t % 3];
        bf16x8 av;
        av[0] = (__bf16)C.a0[0]; av[1] = (__bf16)C.a0[1];
        av[2] = (__bf16)C.a0[2]; av[3] = (__bf16)C.a0[3];
        av[4] = (__bf16)C.a1[0]; av[5] = (__bf16)C.a1[1];
        av[6] = (__bf16)C.a1[2]; av[7] = (__bf16)C.a1[3];
        acc0 = __builtin_amdgcn_mfma_f32_16x16x32_bf16(av, C.b0, acc0, 0, 0, 0);
        acc1 = __builtin_amdgcn_mfma_f32_16x16x32_bf16(av, C.b1, acc1, 0, 0, 0);
        acc2 = __builtin_amdgcn_mfma_f32_16x16x32_bf16(av, C.b2, acc2, 0, 0, 0);
        acc3 = __builtin_amdgcn_mfma_f32_16x16x32_bf16(av, C.b3, acc3, 0, 0, 0);
    }

    // C/D layout: col = lane&15, row = (lane>>4)*4 + reg
#pragma unroll
    for (int i = 0; i < 4; ++i) {
        Ct[wave][lg * 4 + i][ 0 + l15] = acc0[i];
        Ct[wave][lg * 4 + i][16 + l15] = acc1[i];
        Ct[wave][lg * 4 + i][32 + l15] = acc2[i];
        Ct[wave][lg * 4 + i][48 + l15] = acc3[i];
    }
    __syncthreads();

#pragma unroll
    for (int i = 0; i < 2; ++i) {
        int r = wave * 2 + i;
        float hv = 0.f;
#pragma unroll
        for (int w = 0; w < 8; ++w) hv += Ct[w][r][lane];
        float o = epilogue_chain(hv, lane);
        out[(size_t)(rowbase + r) * 64 + lane] = o;
    }
}

extern "C" void kernel_launch(void* const* d_in, const int* in_sizes, int n_in,
                              void* d_out, int out_size, void* d_ws, size_t ws_size,
                              hipStream_t stream)
{
    const float* x      = (const float*)d_in[0];
    const float* adj    = (const float*)d_in[1];
    const float* weight = (const float*)d_in[2];
    const float* bias   = (const float*)d_in[3];
    float* out = (float*)d_out;
    __bf16* l2bfT = (__bf16*)d_ws;   // 64 x 8192 bf16 = 1 MB

    k_prep<<<2048, 256, 0, stream>>>(x, weight, bias, l2bfT);
    k_mm<<<512, 512, 0, stream>>>(adj, l2bfT, out);
}

// Round 5
// 112.215 us; speedup vs baseline: 1.1508x; 1.0203x over previous
//
#include <hip/hip_runtime.h>
#include <hip/hip_bf16.h>
#include <math.h>

typedef __bf16 bf16x8 __attribute__((ext_vector_type(8)));
typedef float  f32x4  __attribute__((ext_vector_type(4)));

#define NND 8192
#define DIM 64
#define CK  256            // K-tile in floats
#define ASTR 260           // LDS row stride (floats): 16B-aligned, bank-offset 4/row

__device__ __forceinline__ float wsum(float v) {
#pragma unroll
    for (int m = 1; m < 64; m <<= 1) v += __shfl_xor(v, m, 64);
    return v;
}

struct SC { float sh, ch; };
__device__ __forceinline__ SC sinhcosh(float c) {
    float e  = expf(c);
    float ei = 1.0f / e;
    SC r; r.sh = 0.5f * (e - ei); r.ch = 0.5f * (e + ei);
    return r;
}

__device__ __forceinline__ float arcosh_from_n2(float n2) {
    float t = fmaxf(n2, 2.0000001e-7f);
    return logf(sqrtf(1.0f + t) + sqrtf(t));
}

__device__ __forceinline__ float tangent_chain(float xv, int lane) {
    float y   = (lane == 0) ? 0.0f : xv;
    float yn2 = wsum(y * y);
    float yn  = fmaxf(sqrtf(fmaxf(yn2, 1e-30f)), 1e-15f);
    SC s1 = sinhcosh(fminf(yn, 15.0f));
    float r   = (lane == 0) ? 0.0f : s1.sh * y / yn;
    float rn2 = wsum(r * r);
    float ynb = fmaxf(sqrtf(fmaxf(rn2, 1e-30f)), 1e-15f);
    float ac  = arcosh_from_n2(rn2);
    return (lane == 0) ? 0.0f : ac * r / ynb;
}

__device__ __forceinline__ float second_chain(float m, float ubv, float theta_b, int lane) {
    float my  = (lane == 0) ? 0.0f : m;
    float mn2 = wsum(my * my);
    float mn  = fmaxf(sqrtf(fmaxf(mn2, 1e-30f)), 1e-15f);
    SC s2 = sinhcosh(fminf(mn, 15.0f));
    float rr   = (lane == 0) ? 0.0f : s2.sh * my / mn;
    float rrn2 = wsum(rr * rr);
    float res0 = sqrtf(fmaxf(1.0f + rrn2, 1e-7f));
    float yn3   = fmaxf(sqrtf(fmaxf(rrn2, 1e-30f)), 1e-15f);
    float yhat  = (lane == 0) ? 0.0f : rr / yn3;
    float alpha = wsum(yhat * ubv);
    float w_    = ubv - alpha * (1.0f - res0) * yhat;
    float ux    = wsum(rr * w_);
    float v0    = ux / fmaxf(res0, 1e-7f);
    float vv    = (lane == 0) ? v0 : w_;
    float resv  = (lane == 0) ? res0 : rr;
    float theta = theta_b;
    SC s3 = sinhcosh(fminf(theta, 15.0f));
    float pv  = s3.ch * resv + s3.sh * vv / theta;
    float pn2 = wsum((lane == 0) ? 0.0f : pv * pv);
    float yn4 = fmaxf(sqrtf(fmaxf(pn2, 1e-30f)), 1e-15f);
    float ac4 = arcosh_from_n2(pn2);
    return (lane == 0) ? 0.0f : ac4 * pv / yn4;
}

__device__ __forceinline__ float epilogue_chain(float hv, int lane) {
    float y   = (lane == 0) ? 0.0f : hv;
    float yn2 = wsum(y * y);
    float yn  = fmaxf(sqrtf(fmaxf(yn2, 1e-30f)), 1e-15f);
    SC s1 = sinhcosh(fminf(yn, 15.0f));
    float r   = (lane == 0) ? 0.0f : s1.sh * y / yn;
    float rn2 = wsum(r * r);
    float ynb = fmaxf(sqrtf(fmaxf(rn2, 1e-30f)), 1e-15f);
    float ac  = arcosh_from_n2(rn2);
    float lgv = (lane == 0) ? 0.0f : ac * r / ynb;
    float t   = (lgv > 0.0f) ? lgv : 0.01f * lgv;
    float tn2 = wsum(t * t);
    float tn  = fmaxf(sqrtf(fmaxf(tn2, 1e-30f)), 1e-15f);
    SC s3 = sinhcosh(fminf(tn, 15.0f));
    float ov  = (lane == 0) ? 0.0f : s3.sh * t / tn;
    float on2 = wsum(ov * ov);
    float o0  = sqrtf(fmaxf(1.0f + on2, 1e-7f));
    return (lane == 0) ? o0 : ov;
}

// Kernel 1: per-row chain + 64x64 matvec; 1 row per wave.
__global__ __launch_bounds__(256) void k_prep(
    const float* __restrict__ x, const float* __restrict__ weight,
    const float* __restrict__ bias, __bf16* __restrict__ l2bfT)
{
    __shared__ float WL[64][65];
    const int tid  = threadIdx.x;
    const int lane = tid & 63;
    const int wave = tid >> 6;
#pragma unroll
    for (int i = 0; i < 16; ++i) {
        int idx = i * 256 + tid;
        WL[idx >> 6][idx & 63] = weight[idx];
    }
    __syncthreads();
    float ubv  = tangent_chain(bias[lane], lane);
    float nub2 = wsum(ubv * ubv);
    float thb  = fmaxf(fminf(sqrtf(fmaxf(nub2, 1e-7f)), 1e6f), 1e-15f);

    const int row = blockIdx.x * 4 + wave;
    float xv  = x[row * 64 + lane];
    float L1v = tangent_chain(xv, lane);
    float mj0 = 0.f, mj1 = 0.f, mj2 = 0.f, mj3 = 0.f;
#pragma unroll
    for (int d = 0; d < 64; d += 4) {
        mj0 = fmaf(__shfl(L1v, d,     64), WL[lane][d],     mj0);
        mj1 = fmaf(__shfl(L1v, d + 1, 64), WL[lane][d + 1], mj1);
        mj2 = fmaf(__shfl(L1v, d + 2, 64), WL[lane][d + 2], mj2);
        mj3 = fmaf(__shfl(L1v, d + 3, 64), WL[lane][d + 3], mj3);
    }
    float mj  = (mj0 + mj1) + (mj2 + mj3);
    float L2v = second_chain(mj, ubv, thb, lane);
    l2bfT[(size_t)lane * NND + row] = (__bf16)L2v;
}

// Kernel 2: h_tan = adj @ L2. LDS-tiled: every global A-load is a lane-major
// contiguous 1KB burst (DRAM page-friendly); MFMA fragments come from LDS.
// 4 waves K-split each 16x256 tile; double-buffered; 1 barrier/tile.
__global__ __launch_bounds__(256, 4) void k_mm(
    const float* __restrict__ adj, const __bf16* __restrict__ l2bfT,
    float* __restrict__ out)
{
    __shared__ float smem[2 * 16 * ASTR];    // 33280 B; reused as Ct after K-loop
    const int tid  = threadIdx.x;
    const int lane = tid & 63;
    const int wave = tid >> 6;     // 0..3
    const int l15  = lane & 15;
    const int lg   = lane >> 4;    // 0..3
    const int rowbase = blockIdx.x * 16;

    // B pointers: NO wave offset here — kg (which contains kf = wave*64+32s)
    // carries the full per-wave K offset. (Round-4 bug: wave*64 was counted twice.)
    const __bf16* bp0 = l2bfT + (size_t)l15 * NND + 8 * lg;
    const __bf16* bp1 = bp0 + (size_t)16 * NND;
    const __bf16* bp2 = bp0 + (size_t)32 * NND;
    const __bf16* bp3 = bp0 + (size_t)48 * NND;

    // staging: wave w loads rows 4w..4w+3, 1KB contiguous per row
    const float* g0 = adj + (size_t)(rowbase + 4 * wave + 0) * NND + 4 * lane;
    const float* g1 = adj + (size_t)(rowbase + 4 * wave + 1) * NND + 4 * lane;
    const float* g2 = adj + (size_t)(rowbase + 4 * wave + 2) * NND + 4 * lane;
    const float* g3 = adj + (size_t)(rowbase + 4 * wave + 3) * NND + 4 * lane;
    float* const wA = smem + (4 * wave) * ASTR + 4 * lane;   // ds_write base (buf0)

    f32x4 acc0 = {0.f, 0.f, 0.f, 0.f};
    f32x4 acc1 = acc0, acc2 = acc0, acc3 = acc0;

    // ---- prologue: stage tile 0 into buf0
    {
        f32x4 s0 = *reinterpret_cast<const f32x4*>(g0);
        f32x4 s1 = *reinterpret_cast<const f32x4*>(g1);
        f32x4 s2 = *reinterpret_cast<const f32x4*>(g2);
        f32x4 s3 = *reinterpret_cast<const f32x4*>(g3);
        *reinterpret_cast<f32x4*>(wA + 0 * ASTR) = s0;
        *reinterpret_cast<f32x4*>(wA + 1 * ASTR) = s1;
        *reinterpret_cast<f32x4*>(wA + 2 * ASTR) = s2;
        *reinterpret_cast<f32x4*>(wA + 3 * ASTR) = s3;
    }
    __syncthreads();

#pragma unroll 2
    for (int t = 0; t < 32; ++t) {
        const int cur = t & 1;
        f32x4 s0, s1, s2, s3;
        const bool pf = (t < 31);
        if (pf) {                               // issue next-tile loads EARLY
            const int ko = (t + 1) * CK;
            s0 = *reinterpret_cast<const f32x4*>(g0 + ko);
            s1 = *reinterpret_cast<const f32x4*>(g1 + ko);
            s2 = *reinterpret_cast<const f32x4*>(g2 + ko);
            s3 = *reinterpret_cast<const f32x4*>(g3 + ko);
        }
        // compute current tile: waves K-split (64 floats each), 2 k-steps of 32
        const float* Ab = smem + cur * (16 * ASTR);
#pragma unroll
        for (int s = 0; s < 2; ++s) {
            const int kf = wave * 64 + 32 * s;
            const float* ar = Ab + l15 * ASTR + kf + 8 * lg;
            f32x4 a0 = *reinterpret_cast<const f32x4*>(ar);
            f32x4 a1 = *reinterpret_cast<const f32x4*>(ar + 4);
            bf16x8 av;
            av[0] = (__bf16)a0[0]; av[1] = (__bf16)a0[1];
            av[2] = (__bf16)a0[2]; av[3] = (__bf16)a0[3];
            av[4] = (__bf16)a1[0]; av[5] = (__bf16)a1[1];
            av[6] = (__bf16)a1[2]; av[7] = (__bf16)a1[3];
            const int kg = t * CK + kf;         // full k offset for B (incl. wave)
            bf16x8 b0 = *reinterpret_cast<const bf16x8*>(bp0 + kg);
            bf16x8 b1 = *reinterpret_cast<const bf16x8*>(bp1 + kg);
            bf16x8 b2 = *reinterpret_cast<const bf16x8*>(bp2 + kg);
            bf16x8 b3 = *reinterpret_cast<const bf16x8*>(bp3 + kg);
            acc0 = __builtin_amdgcn_mfma_f32_16x16x32_bf16(av, b0, acc0, 0, 0, 0);
            acc1 = __builtin_amdgcn_mfma_f32_16x16x32_bf16(av, b1, acc1, 0, 0, 0);
            acc2 = __builtin_amdgcn_mfma_f32_16x16x32_bf16(av, b2, acc2, 0, 0, 0);
            acc3 = __builtin_amdgcn_mfma_f32_16x16x32_bf16(av, b3, acc3, 0, 0, 0);
        }
        if (pf) {                               // write staged regs LATE
            float* wN = smem + (cur ^ 1) * (16 * ASTR) + (4 * wave) * ASTR + 4 * lane;
            *reinterpret_cast<f32x4*>(wN + 0 * ASTR) = s0;
            *reinterpret_cast<f32x4*>(wN + 1 * ASTR) = s1;
            *reinterpret_cast<f32x4*>(wN + 2 * ASTR) = s2;
            *reinterpret_cast<f32x4*>(wN + 3 * ASTR) = s3;
        }
        __syncthreads();                        // publishes next tile / guards reuse
    }

    // ---- epilogue: reuse smem for cross-wave partial sums
    float (*Ct)[16][65] = reinterpret_cast<float (*)[16][65]>(smem);
#pragma unroll
    for (int i = 0; i < 4; ++i) {
        Ct[wave][lg * 4 + i][ 0 + l15] = acc0[i];
        Ct[wave][lg * 4 + i][16 + l15] = acc1[i];
        Ct[wave][lg * 4 + i][32 + l15] = acc2[i];
        Ct[wave][lg * 4 + i][48 + l15] = acc3[i];
    }
    __syncthreads();

#pragma unroll
    for (int i = 0; i < 4; ++i) {
        int r = wave * 4 + i;
        float hv = Ct[0][r][lane] + Ct[1][r][lane] + Ct[2][r][lane] + Ct[3][r][lane];
        float o  = epilogue_chain(hv, lane);
        out[(size_t)(rowbase + r) * 64 + lane] = o;
    }
}

extern "C" void kernel_launch(void* const* d_in, const int* in_sizes, int n_in,
                              void* d_out, int out_size, void* d_ws, size_t ws_size,
                              hipStream_t stream)
{
    const float* x      = (const float*)d_in[0];
    const float* adj    = (const float*)d_in[1];
    const float* weight = (const float*)d_in[2];
    const float* bias   = (const float*)d_in[3];
    float* out = (float*)d_out;
    __bf16* l2bfT = (__bf16*)d_ws;   // 64 x 8192 bf16 = 1 MB

    k_prep<<<2048, 256, 0, stream>>>(x, weight, bias, l2bfT);
    k_mm<<<512, 256, 0, stream>>>(adj, l2bfT, out);
}